// Round 4
// baseline (6073.873 us; speedup 1.0000x reference)
//
#include <hip/hip_runtime.h>

#define MFMA16 __builtin_amdgcn_mfma_f32_16x16x32_bf16
#define SGB    __builtin_amdgcn_sched_group_barrier

typedef __attribute__((ext_vector_type(8))) short short8;
typedef __attribute__((ext_vector_type(4))) float floatx4;

static constexpr int T_STEPS = 50;
static constexpr int BATCH   = 1024;
static constexpr int SDIM    = 32;
static constexpr int DDIM    = 600;
static constexpr int ADIM    = 6;
static constexpr int KP      = 608;   // padded K/N per gate
static constexpr int PITCH   = 616;   // LDS row pitch (shorts)
static constexpr int SAPITCH = 72;
static constexpr int NTHREADS = 512;  // 8 waves; 2 wgs/CU (LDS 61440*2 < 160K)
static constexpr int NSLICE  = 8;     // wgid%8 == slice == XCD id -> ~0.9MB weights/XCD

// workspace layout (ushort offsets)
static constexpr size_t SZ608    = (size_t)608 * 608;
static constexpr size_t OFF_WIHR = 0;
static constexpr size_t OFF_WIHZ = OFF_WIHR + SZ608;
static constexpr size_t OFF_WIHN = OFF_WIHZ + SZ608;
static constexpr size_t OFF_WHHR = OFF_WIHN + SZ608;
static constexpr size_t OFF_WHHZ = OFF_WHHR + SZ608;
static constexpr size_t OFF_WHHN = OFF_WHHZ + SZ608;
static constexpr size_t OFF_WP1  = OFF_WHHN + SZ608;
static constexpr size_t OFF_WQ1D = OFF_WP1  + SZ608;
static constexpr size_t OFF_WQ1E = OFF_WQ1D + SZ608;              // [608][1024]
static constexpr size_t OFF_WSA  = OFF_WQ1E + (size_t)608 * 1024; // [608][64]
static constexpr size_t OFF_WHEAD= OFF_WSA  + (size_t)608 * 64;   // [128][608]
static constexpr size_t OFF_PREQ = OFF_WHEAD+ (size_t)128 * 608;  // [50*1024][600] bf16
static constexpr size_t OFF_DETG = OFF_PREQ + (size_t)T_STEPS * BATCH * 600; // [1024][608] bf16
static constexpr size_t OFF_BAR  = OFF_DETG + (size_t)BATCH * KP;            // 64 ints
static constexpr size_t OFF_PART = OFF_BAR + 256;                 // [64][8][16][128] f32 (4MB)

// output offsets (fp32 elements), reference return order
static constexpr size_t O_PM = 0;
static constexpr size_t O_PS = 1638400;
static constexpr size_t O_PR = 3276800;
static constexpr size_t O_D1 = 4915200;
static constexpr size_t O_QM = 35635200;
static constexpr size_t O_QS = 37273600;
static constexpr size_t O_PO = 38912000;
static constexpr size_t O_D2 = 40550400;

__device__ __forceinline__ unsigned short f2bf(float f) {
  unsigned u = __float_as_uint(f);
  u += 0x7FFFu + ((u >> 16) & 1u);   // RNE
  return (unsigned short)(u >> 16);
}
__device__ __forceinline__ float bf2f(unsigned short u) {
  return __uint_as_float(((unsigned)u) << 16);
}
__device__ __forceinline__ float elu_f(float v) { return v > 0.f ? v : expm1f(v); }
__device__ __forceinline__ float sigmoid_f(float x) { return 1.f / (1.f + expf(-x)); }
__device__ __forceinline__ float tanh_f(float x) {
  x = fminf(fmaxf(x, -15.f), 15.f);
  float e = expf(2.f * x);
  return (e - 1.f) / (e + 1.f);
}

// ---------------- prep: stage weights as bf16, padded/split per gate ----------------
__global__ __launch_bounds__(256) void stage_weights(
    const float* __restrict__ Win, const float* __restrict__ Wih, const float* __restrict__ Whh,
    const float* __restrict__ Wp1, const float* __restrict__ Wq1,
    const float* __restrict__ Wp2, const float* __restrict__ Wq2,
    unsigned short* __restrict__ ws)
{
  const int region = blockIdx.y;
  if (region == 11) {           // zero the per-bgroup barrier counters each launch
    if (blockIdx.x == 0 && threadIdx.x < 64)
      ((int*)(ws + OFF_BAR))[threadIdx.x] = 0;
    return;
  }
  int R = 608, C = 608;
  size_t dst = 0;
  switch (region) {
    case 0: dst = OFF_WIHR; break;
    case 1: dst = OFF_WIHZ; break;
    case 2: dst = OFF_WIHN; break;
    case 3: dst = OFF_WHHR; break;
    case 4: dst = OFF_WHHZ; break;
    case 5: dst = OFF_WHHN; break;
    case 6: dst = OFF_WP1;  break;
    case 7: dst = OFF_WQ1D; break;
    case 8: dst = OFF_WQ1E; C = 1024; break;
    case 9: dst = OFF_WSA;  C = 64;   break;
    case 10: dst = OFF_WHEAD; R = 128; break;
  }
  const int total = R * C;
  for (int e = blockIdx.x * 256 + threadIdx.x; e < total; e += gridDim.x * 256) {
    int n = e / C, k = e - n * C;
    float v = 0.f;
    switch (region) {
      case 0: if (n < 600 && k < 600) v = Wih[(size_t)n * 600 + k]; break;
      case 1: if (n < 600 && k < 600) v = Wih[(size_t)(600 + n) * 600 + k]; break;
      case 2: if (n < 600 && k < 600) v = Wih[(size_t)(1200 + n) * 600 + k]; break;
      case 3: if (n < 600 && k < 600) v = Whh[(size_t)n * 600 + k]; break;
      case 4: if (n < 600 && k < 600) v = Whh[(size_t)(600 + n) * 600 + k]; break;
      case 5: if (n < 600 && k < 600) v = Whh[(size_t)(1200 + n) * 600 + k]; break;
      case 6: if (n < 600 && k < 600) v = Wp1[(size_t)n * 600 + k]; break;
      case 7: if (n < 600 && k < 600) v = Wq1[(size_t)n * 1624 + k]; break;
      case 8: if (n < 600) v = Wq1[(size_t)n * 1624 + 600 + k]; break;
      case 9: if (n < 600) { if (k < 32) v = Win[(size_t)n * 38 + 6 + k];
                             else if (k < 38) v = Win[(size_t)n * 38 + (k - 32)]; } break;
      case 10: if (k < 600) v = (n < 64) ? Wp2[(size_t)n * 600 + k]
                                         : Wq2[(size_t)(n - 64) * 600 + k]; break;
    }
    ws[dst + (size_t)e] = f2bf(v);
  }
}

// ---------------- prep: pre_q[t,b,:] = enc[t,b,:] @ Wq1[:,600:].T + bq1 (bf16 out) ----------------
__global__ __launch_bounds__(256) void preq_gemm(
    const float* __restrict__ enc, const float* __restrict__ bq1,
    const unsigned short* __restrict__ ws, unsigned short* __restrict__ preq)
{
  __shared__ unsigned short A[16 * 1032];
  const size_t g0 = (size_t)blockIdx.x * 16;
  const int tid = threadIdx.x;

  const float4* e4 = (const float4*)(enc + g0 * 1024);
  for (int i = tid; i < 16 * 256; i += 256) {
    int row = i >> 8, c4 = i & 255;
    float4 v = e4[row * 256 + c4];
    int base = row * 1032 + c4 * 4;
    A[base + 0] = f2bf(v.x); A[base + 1] = f2bf(v.y);
    A[base + 2] = f2bf(v.z); A[base + 3] = f2bf(v.w);
  }
  __syncthreads();

  const int wave = tid >> 6, lane = tid & 63, q = lane >> 4, l15 = lane & 15;
  const unsigned short* Wq1e = ws + OFF_WQ1E;
  for (int tile = wave; tile < 38; tile += 4) {
    const int n0 = tile * 16;
    floatx4 acc = {0.f, 0.f, 0.f, 0.f};
    const unsigned short* wb = Wq1e + (size_t)(n0 + l15) * 1024 + q * 8;
    const int aoff = l15 * 1032 + q * 8;
    for (int ki = 0; ki < 32; ++ki) {
      short8 a = *(const short8*)(&A[aoff + ki * 32]);
      short8 b = *(const short8*)(wb + ki * 32);
      acc = MFMA16(a, b, acc, 0, 0, 0);
    }
    const int col = n0 + l15;
    if (col < 600) {
      float bb = bq1[col];
      for (int i = 0; i < 4; ++i) {
        int row = q * 4 + i;
        preq[(g0 + row) * 600 + col] = f2bf(acc[i] + bb);
      }
    }
  }
}

// ---------------- main rollout: 512 wgs = 64 batch-groups x 8 N-slices, 2 wgs/CU ------------
// slice = wgid & 7 == XCD id  -> per-XCD weight slice ~0.9MB, robustly L2-resident.
// Two wgs per CU belong to DIFFERENT batch-groups (wgid, wgid+256) with independent
// barriers -> phases decorrelate and cover each other's latency stalls.
// Cross-XCD traffic (DETG, PART) volatile (LLC-coherent); barrier flags RELAXED atomics.
// P1/P2: depth-2 register prefetch + sched_group_barrier [VMEM][DS][MFMA] clustering.
__global__ __launch_bounds__(NTHREADS)
__attribute__((amdgpu_waves_per_eu(4)))   // cap 128 VGPR so 2 wgs (16 waves) co-reside
void rssm_rollout(
    const float* __restrict__ actions, const float* __restrict__ init_stoch,
    const float* __restrict__ init_det,
    const float* __restrict__ eps_p, const float* __restrict__ eps_q,
    const float* __restrict__ b_in, const float* __restrict__ b_ih, const float* __restrict__ b_hh,
    const float* __restrict__ bp1, const float* __restrict__ bp2, const float* __restrict__ bq2,
    unsigned short* __restrict__ wsm, float* __restrict__ out)
{
  __shared__ unsigned short XB[16 * PITCH];   // rnn_in; h_p after P2
  __shared__ unsigned short DC[16 * PITCH];   // det (old; refreshed to det_new after sync A)
  __shared__ unsigned short HQ[16 * PITCH];   // h_q
  __shared__ unsigned short SA[16 * SAPITCH]; // [stoch(32)|act(6)|pad] bf16

  const unsigned short* ws = wsm;
  const int tid  = threadIdx.x;
  const int wave = tid >> 6, lane = tid & 63, q = lane >> 4, l15 = lane & 15;
  const int wg    = blockIdx.x;
  const int slice = wg & 7;
  const int bg    = wg >> 3;
  const int brow0 = bg * 16;
  const int ntile = (slice < 6) ? 5 : 4;                      // 6*5 + 2*4 = 38 tiles
  const int tile0 = (slice < 6) ? slice * 5 : 30 + (slice - 6) * 4;
  const int cs    = tile0 * 16;                               // owned col base
  const int Wd    = ntile * 16;                               // owned col width

  unsigned short* DETG = wsm + OFF_DETG;
  int*   bar  = (int*)(wsm + OFF_BAR);
  float* PART = (float*)(wsm + OFF_PART);
  const unsigned short* preq = ws + OFF_PREQ;

  float* out_pm = out + O_PM; float* out_ps = out + O_PS; float* out_pr = out + O_PR;
  float* out_d1 = out + O_D1; float* out_qm = out + O_QM; float* out_qs = out + O_QS;
  float* out_po = out + O_PO; float* out_d2 = out + O_D2;

  int phase = 0;
  auto bgsync = [&]() {   // 8-wg barrier per batch-group, RELAXED (no cache maintenance)
    __syncthreads();
    ++phase;
    if (tid == 0) {
      __hip_atomic_fetch_add(&bar[bg], 1, __ATOMIC_RELAXED, __HIP_MEMORY_SCOPE_AGENT);
      while (__hip_atomic_load(&bar[bg], __ATOMIC_RELAXED, __HIP_MEMORY_SCOPE_AGENT) < NSLICE * phase)
        __builtin_amdgcn_s_sleep(2);
    }
    __syncthreads();
    asm volatile("" ::: "memory");
  };

  auto do_reduce = [&](int tcur) {  // combine head partials of step (tcur-1); fill SA; write outs
    const volatile float* part = (const volatile float*)(PART + (size_t)bg * (8 * 16 * 128));
    {
      const int r = tid >> 5, c = tid & 31;   // NTHREADS==512 -> all threads, r<16
      const volatile float* P0 = part + (0 * 16 + r) * 128;
      const volatile float* P1 = part + (1 * 16 + r) * 128;
      const volatile float* P2 = part + (2 * 16 + r) * 128;
      const volatile float* P3 = part + (3 * 16 + r) * 128;
      const volatile float* P4 = part + (4 * 16 + r) * 128;
      const volatile float* P5 = part + (5 * 16 + r) * 128;
      const volatile float* P6 = part + (6 * 16 + r) * 128;
      const volatile float* P7 = part + (7 * 16 + r) * 128;
      float m0 = P0[c], s0 = P0[32+c], u0 = P0[64+c], v0 = P0[96+c];
      float m1 = P1[c], s1 = P1[32+c], u1 = P1[64+c], v1 = P1[96+c];
      float m2 = P2[c], s2 = P2[32+c], u2 = P2[64+c], v2 = P2[96+c];
      float m3 = P3[c], s3 = P3[32+c], u3 = P3[64+c], v3 = P3[96+c];
      float m4 = P4[c], s4 = P4[32+c], u4 = P4[64+c], v4 = P4[96+c];
      float m5 = P5[c], s5 = P5[32+c], u5 = P5[64+c], v5 = P5[96+c];
      float m6 = P6[c], s6 = P6[32+c], u6 = P6[64+c], v6 = P6[96+c];
      float m7 = P7[c], s7 = P7[32+c], u7 = P7[64+c], v7 = P7[96+c];
      float pm  = bp2[c]      + (((m0+m1)+(m2+m3)) + ((m4+m5)+(m6+m7)));
      float psr = bp2[32 + c] + (((s0+s1)+(s2+s3)) + ((s4+s5)+(s6+s7)));
      float qm  = bq2[c]      + (((u0+u1)+(u2+u3)) + ((u4+u5)+(u6+u7)));
      float qsr = bq2[32 + c] + (((v0+v1)+(v2+v3)) + ((v4+v5)+(v6+v7)));
      const size_t oidx = ((size_t)(tcur - 1) * BATCH + brow0 + r) * SDIM + c;
      const float qs = (qsr > 30.f ? qsr : log1pf(expf(qsr))) + 0.1f;
      const float x  = qm + qs * __builtin_nontemporal_load(&eps_q[oidx]);
      SA[r * SAPITCH + c] = f2bf(x);          // stoch carry
      if (slice == 0) {
        const float ps = (psr > 30.f ? psr : log1pf(expf(psr))) + 0.1f;
        __builtin_nontemporal_store(pm, &out_pm[oidx]);
        __builtin_nontemporal_store(ps, &out_ps[oidx]);
        __builtin_nontemporal_store(pm + ps * __builtin_nontemporal_load(&eps_p[oidx]),
                                    &out_pr[oidx]);
      } else if (slice == 1) {
        __builtin_nontemporal_store(qm, &out_qm[oidx]);
        __builtin_nontemporal_store(qs, &out_qs[oidx]);
        __builtin_nontemporal_store(x,  &out_po[oidx]);
      }
    }
  };

  for (int t = 0; t < T_STEPS; ++t) {
    // ---- top of step: SA fill (init or reduce of prev heads) + stage act[t]
    if (t == 0) {
      for (int i = tid; i < 16 * PITCH; i += NTHREADS) { XB[i] = 0; DC[i] = 0; HQ[i] = 0; }
      for (int i = tid; i < 16 * SAPITCH; i += NTHREADS) SA[i] = 0;
      __syncthreads();
      for (int i = tid; i < 16 * SDIM; i += NTHREADS) {
        int r = i >> 5, c = i & 31;
        SA[r * SAPITCH + c] = f2bf(init_stoch[(size_t)(brow0 + r) * SDIM + c]);
      }
      for (int i = tid; i < 16 * DDIM; i += NTHREADS) {
        int r = i / DDIM, k = i - r * DDIM;
        DC[r * PITCH + k] = f2bf(init_det[(size_t)(brow0 + r) * DDIM + k]);
      }
      if (tid < 128) {  // zero DETG pad cols (600..607) for this bgroup
        int r = tid >> 3, c = 600 + (tid & 7);
        *(volatile unsigned short*)&DETG[(size_t)(brow0 + r) * KP + c] = 0;
      }
    } else {
      do_reduce(t);
    }
    if (tid < 96) {
      int r = tid / 6, j = tid - r * 6;
      SA[r * SAPITCH + 32 + j] = f2bf(actions[((size_t)t * BATCH + brow0 + r) * ADIM + j]);
    }
    __syncthreads();

    // ---- P0b: rnn_in = elu([stoch|act] @ Wsa.T + b_in) -> XB, full width (cheap, redundant)
    for (int tile = wave; tile < 38; tile += 8) {
      const int n0 = tile * 16;
      floatx4 acc = {0.f, 0.f, 0.f, 0.f};
      const unsigned short* wb = ws + OFF_WSA + (size_t)(n0 + l15) * 64 + q * 8;
      const int aoff = l15 * SAPITCH + q * 8;
      short8 a0 = *(const short8*)(&SA[aoff]);
      short8 a1 = *(const short8*)(&SA[aoff + 32]);
      short8 b0 = *(const short8*)(wb);
      short8 b1 = *(const short8*)(wb + 32);
      acc = MFMA16(a0, b0, acc, 0, 0, 0);
      acc = MFMA16(a1, b1, acc, 0, 0, 0);
      const int col = n0 + l15;
      if (col < DDIM) {
        float bi = b_in[col];
        for (int i = 0; i < 4; ++i)
          XB[(q * 4 + i) * PITCH + col] = f2bf(elu_f(acc[i] + bi));
      }
    }
    __syncthreads();

    // ---- P1: GRU for owned col tiles -> DETG + outputs d1/d2
    // depth-2 register prefetch (3 named sets) + sched_group_barrier clustering
    if (wave < ntile) {
      const int n0 = (tile0 + wave) * 16;
      floatx4 aIr = {0,0,0,0}, aIz = {0,0,0,0}, aIn = {0,0,0,0};
      floatx4 aHr = {0,0,0,0}, aHz = {0,0,0,0}, aHn = {0,0,0,0};
      const size_t wrow = (size_t)(n0 + l15) * KP + q * 8;
      const unsigned short* pIr = ws + OFF_WIHR + wrow;
      const unsigned short* pIz = ws + OFF_WIHZ + wrow;
      const unsigned short* pIn = ws + OFF_WIHN + wrow;
      const unsigned short* pHr = ws + OFF_WHHR + wrow;
      const unsigned short* pHz = ws + OFF_WHHZ + wrow;
      const unsigned short* pHn = ws + OFF_WHHN + wrow;
      const int aoff = l15 * PITCH + q * 8;
      short8 aIrc, aIzc, aInc, aHrc, aHzc, aHnc;   // cur
      short8 bIrc, bIzc, bInc, bHrc, bHzc, bHnc;   // +1
      short8 cIrc, cIzc, cInc, cHrc, cHzc, cHnc;   // +2
#define LD6(S, o) \
      S##Irc = *(const short8*)(pIr + (o)); S##Izc = *(const short8*)(pIz + (o)); \
      S##Inc = *(const short8*)(pIn + (o)); S##Hrc = *(const short8*)(pHr + (o)); \
      S##Hzc = *(const short8*)(pHz + (o)); S##Hnc = *(const short8*)(pHn + (o));
      LD6(a, 0)
      LD6(b, 32)
      #pragma unroll
      for (int ki = 0; ki < 19; ++ki) {
        if (ki < 17) { LD6(c, (ki + 2) * 32) }
        short8 ax = *(const short8*)(&XB[aoff + ki * 32]);
        short8 ad = *(const short8*)(&DC[aoff + ki * 32]);
        aIr = MFMA16(ax, aIrc, aIr, 0, 0, 0);
        aIz = MFMA16(ax, aIzc, aIz, 0, 0, 0);
        aIn = MFMA16(ax, aInc, aIn, 0, 0, 0);
        aHr = MFMA16(ad, aHrc, aHr, 0, 0, 0);
        aHz = MFMA16(ad, aHzc, aHz, 0, 0, 0);
        aHn = MFMA16(ad, aHnc, aHn, 0, 0, 0);
        SGB(0x20, 6, 0);   // 6 VMEM_READ (prefetch ki+2)
        SGB(0x100, 2, 0);  // 2 DS_READ   (A operands ki)
        SGB(0x8, 6, 0);    // 6 MFMA      (ki)
        aIrc = bIrc; aIzc = bIzc; aInc = bInc; aHrc = bHrc; aHzc = bHzc; aHnc = bHnc;
        bIrc = cIrc; bIzc = cIzc; bInc = cInc; bHrc = cHrc; bHzc = cHzc; bHnc = cHnc;
      }
#undef LD6
      const int d = n0 + l15;
      if (d < DDIM) {
        float bihr = b_ih[d],        bhhr = b_hh[d];
        float bihz = b_ih[600 + d],  bhhz = b_hh[600 + d];
        float bihn = b_ih[1200 + d], bhhn = b_hh[1200 + d];
        for (int i = 0; i < 4; ++i) {
          int row = q * 4 + i;
          float r = sigmoid_f(aIr[i] + aHr[i] + bihr + bhhr);
          float z = sigmoid_f(aIz[i] + aHz[i] + bihz + bhhz);
          float n = tanh_f(aIn[i] + bihn + r * (aHn[i] + bhhn));
          float dprev = bf2f(DC[row * PITCH + d]);
          float dn = (1.f - z) * n + z * dprev;
          *(volatile unsigned short*)&DETG[(size_t)(brow0 + row) * KP + d] = f2bf(dn);
          size_t oidx = ((size_t)t * BATCH + brow0 + row) * DDIM + d;
          __builtin_nontemporal_store(dn, &out_d1[oidx]);
          __builtin_nontemporal_store(dn, &out_d2[oidx]);
        }
      }
    }
    bgsync();   // sync A: det_new complete across the bgroup's 8 slices

    // ---- load full det_new -> DC (5 batched volatile loads in flight)
    {
      const volatile unsigned long long* src =
          (const volatile unsigned long long*)DETG;   // 608 shorts = 152 x 8B per row
      const int i0 = tid, i1 = tid + 512, i2 = tid + 1024, i3 = tid + 1536, i4 = tid + 2048;
      const int r0 = i0 / 152, c0 = i0 - r0 * 152;
      const int r1 = i1 / 152, c1 = i1 - r1 * 152;
      const int r2 = i2 / 152, c2 = i2 - r2 * 152;
      const int r3 = i3 / 152, c3 = i3 - r3 * 152;
      const int r4 = i4 / 152, c4 = i4 - r4 * 152;
      unsigned long long v0, v1, v2, v3, v4 = 0;
      v0 = src[(size_t)(brow0 + r0) * 152 + c0];
      v1 = src[(size_t)(brow0 + r1) * 152 + c1];
      v2 = src[(size_t)(brow0 + r2) * 152 + c2];
      v3 = src[(size_t)(brow0 + r3) * 152 + c3];
      if (i4 < 2432) v4 = src[(size_t)(brow0 + r4) * 152 + c4];
      *(unsigned long long*)(&DC[r0 * PITCH + c0 * 4]) = v0;
      *(unsigned long long*)(&DC[r1 * PITCH + c1 * 4]) = v1;
      *(unsigned long long*)(&DC[r2 * PITCH + c2 * 4]) = v2;
      *(unsigned long long*)(&DC[r3 * PITCH + c3 * 4]) = v3;
      if (i4 < 2432) *(unsigned long long*)(&DC[r4 * PITCH + c4 * 4]) = v4;
    }
    __syncthreads();

    // ---- P2: h_p -> XB, h_q -> HQ for owned tiles (depth-2 prefetch + SGB)
    if (wave < ntile) {
      const int n0 = (tile0 + wave) * 16;
      floatx4 accP = {0,0,0,0}, accQ = {0,0,0,0};
      const size_t wrow = (size_t)(n0 + l15) * KP + q * 8;
      const unsigned short* pP = ws + OFF_WP1  + wrow;
      const unsigned short* pQ = ws + OFF_WQ1D + wrow;
      const int aoff = l15 * PITCH + q * 8;
      short8 b0P, b0Q, b1P, b1Q, b2P, b2Q;
      b0P = *(const short8*)(pP);      b0Q = *(const short8*)(pQ);
      b1P = *(const short8*)(pP + 32); b1Q = *(const short8*)(pQ + 32);
      #pragma unroll
      for (int ki = 0; ki < 19; ++ki) {
        if (ki < 17) {
          const int o = (ki + 2) * 32;
          b2P = *(const short8*)(pP + o); b2Q = *(const short8*)(pQ + o);
        }
        short8 a = *(const short8*)(&DC[aoff + ki * 32]);
        accP = MFMA16(a, b0P, accP, 0, 0, 0);
        accQ = MFMA16(a, b0Q, accQ, 0, 0, 0);
        SGB(0x20, 2, 0);   // 2 VMEM_READ (prefetch ki+2)
        SGB(0x100, 1, 0);  // 1 DS_READ
        SGB(0x8, 2, 0);    // 2 MFMA
        b0P = b1P; b0Q = b1Q; b1P = b2P; b1Q = b2Q;
      }
      const int col = n0 + l15;
      if (col < DDIM) {
        float bb = bp1[col];
        for (int i = 0; i < 4; ++i) {
          int row = q * 4 + i;
          XB[row * PITCH + col] = f2bf(elu_f(accP[i] + bb));
          float pre = bf2f(__builtin_nontemporal_load(
              &preq[((size_t)t * BATCH + brow0 + row) * 600 + col]));
          HQ[row * PITCH + col] = f2bf(elu_f(accQ[i] + pre));
        }
      }
    }
    __syncthreads();

    // ---- P3: head K-partials over owned cols -> PART[bg][slice][16][128]
    // uniform 3 masked 32-col chunks starting at k0 = floor(cs/32); lane-level
    // zeroing of A outside [cs, cs+Wd) (boundaries are 16-aligned = 2 lanes).
    {
      const int h0 = wave * 16;                       // 8 waves: rows 0-63 prior, 64-127 post
      const unsigned short* Asrc = (wave < 4) ? XB : HQ;
      const int k0 = cs >> 5;
      const unsigned short* pW = ws + OFF_WHEAD + (size_t)(h0 + l15) * KP + k0 * 32 + q * 8;
      const int abase = l15 * PITCH + k0 * 32 + q * 8;
      const int colq = k0 * 32 + q * 8;
      short8 zz = {0, 0, 0, 0, 0, 0, 0, 0};
      short8 a0 = *(const short8*)(&Asrc[abase]);
      short8 a1 = *(const short8*)(&Asrc[abase + 32]);
      short8 a2 = *(const short8*)(&Asrc[abase + 64]);
      short8 w0 = *(const short8*)(pW);
      short8 w1 = *(const short8*)(pW + 32);
      short8 w2 = *(const short8*)(pW + 64);
      if (colq      < cs || colq      >= cs + Wd) a0 = zz;
      if (colq + 32 < cs || colq + 32 >= cs + Wd) a1 = zz;
      if (colq + 64 < cs || colq + 64 >= cs + Wd) a2 = zz;
      floatx4 acc = {0,0,0,0};
      acc = MFMA16(a0, w0, acc, 0, 0, 0);
      acc = MFMA16(a1, w1, acc, 0, 0, 0);
      acc = MFMA16(a2, w2, acc, 0, 0, 0);
      volatile float* pdst = (volatile float*)(PART + (size_t)(bg * 8 + slice) * (16 * 128));
      for (int i = 0; i < 4; ++i)
        pdst[(q * 4 + i) * 128 + h0 + l15] = acc[i];
    }
    bgsync();   // sync B: partials visible for next step's reduce
  }

  do_reduce(T_STEPS);   // emit final step's head outputs
}

extern "C" void kernel_launch(void* const* d_in, const int* in_sizes, int n_in,
                              void* d_out, int out_size, void* d_ws, size_t ws_size,
                              hipStream_t stream) {
  const float* enc    = (const float*)d_in[1];
  const float* act    = (const float*)d_in[2];
  const float* init_s = (const float*)d_in[3];
  const float* init_d = (const float*)d_in[4];
  const float* np_    = (const float*)d_in[5];
  const float* nq_    = (const float*)d_in[6];
  const float* Win    = (const float*)d_in[7];
  const float* b_in   = (const float*)d_in[8];
  const float* Wih    = (const float*)d_in[9];
  const float* Whh    = (const float*)d_in[10];
  const float* bih    = (const float*)d_in[11];
  const float* bhh    = (const float*)d_in[12];
  const float* Wp1    = (const float*)d_in[13];
  const float* bp1    = (const float*)d_in[14];
  const float* Wp2    = (const float*)d_in[15];
  const float* bp2    = (const float*)d_in[16];
  const float* Wq1    = (const float*)d_in[17];
  const float* bq1    = (const float*)d_in[18];
  const float* Wq2    = (const float*)d_in[19];
  const float* bq2    = (const float*)d_in[20];
  unsigned short* ws  = (unsigned short*)d_ws;
  float* out = (float*)d_out;

  stage_weights<<<dim3(256, 12), 256, 0, stream>>>(Win, Wih, Whh, Wp1, Wq1, Wp2, Wq2, ws);
  preq_gemm<<<3200, 256, 0, stream>>>(enc, bq1, ws, ws + OFF_PREQ);
  rssm_rollout<<<512, NTHREADS, 0, stream>>>(act, init_s, init_d, np_, nq_,
                                             b_in, bih, bhh, bp1, bp2, bq2, ws, out);
}